// Round 12
// baseline (234.962 us; speedup 1.0000x reference)
//
#include <hip/hip_runtime.h>
#include <hip/hip_bf16.h>

#define B_    2
#define S_    2048
#define H_    15
#define KVH_  5
#define G_    3
#define D_    64
#define KVD_  (KVH_ * D_)      // 320
#define HD_   (H_ * D_)        // 960
#define SW_   (S_ / 32)        // 64 mask words per row
#define KBLK  32
#define NBLK  960              // B*H*(S/64)

constexpr float SCALE   = 0.125f;      // 64^-0.5 (exact pow2, folded into Q)
constexpr float NEG_BIG = -3.0e38f;
constexpr float DEFER_THR = 8.0f;      // defer-max rescale threshold (T13)

typedef __bf16  bf16x8 __attribute__((ext_vector_type(8)));
typedef __bf16  bf16x4 __attribute__((ext_vector_type(4)));
typedef float   f32x4  __attribute__((ext_vector_type(4)));
typedef int     i32x4  __attribute__((ext_vector_type(4)));

#define MFMA(a, b, c) __builtin_amdgcn_mfma_f32_16x16x32_bf16((a), (b), (c), 0, 0, 0)

// async global->LDS, 16B per lane; LDS dest is wave-uniform base, lane i lands at base+i*16
__device__ __forceinline__ void gload16(const void* g, void* l) {
    __builtin_amdgcn_global_load_lds(
        (const __attribute__((address_space(1))) unsigned int*)g,
        (__attribute__((address_space(3))) unsigned int*)l, 16, 0, 0);
}

// pack top-16-bits of two f32 into one bf16x2 word: low16 = trunc-bf16(even), high16 = trunc-bf16(odd)
__device__ __forceinline__ unsigned pack_hi16(unsigned even_elem, unsigned odd_elem) {
    return __builtin_amdgcn_perm(odd_elem, even_elem, 0x07060302u);
}

// ---------------- pre-pass 1: mask (int32 0/1) -> bitmask (grid-stride, 2048 wgs) ----------------
__global__ __launch_bounds__(256) void bitpack(const int* __restrict__ mask,
                                               unsigned int* __restrict__ bits) {
    const int stride = gridDim.x * 256;
    const int lane   = threadIdx.x & 63;
    for (int i = blockIdx.x * 256 + threadIdx.x; i < B_ * S_ * S_; i += stride) {
        unsigned long long bal = __ballot(mask[i] != 0);
        if (lane == 0)       bits[i >> 5] = (unsigned int)bal;
        else if (lane == 32) bits[i >> 5] = (unsigned int)(bal >> 32);
    }
}

// ---------------- pre-pass 2: K fp32 -> bf16 hi/lo (same layout) ----------------
__global__ __launch_bounds__(256) void conv_k(const float* __restrict__ K,
                                              __bf16* __restrict__ khi,
                                              __bf16* __restrict__ klo) {
    const int i = blockIdx.x * 256 + threadIdx.x;          // over (B*S*KVH*D)/4
    const float4 v = ((const float4*)K)[i];
    const float xs[4] = {v.x, v.y, v.z, v.w};
    bf16x4 h, lo;
#pragma unroll
    for (int j = 0; j < 4; j++) {
        __bf16 hh = (__bf16)xs[j];
        h[j]  = hh;
        lo[j] = (__bf16)(xs[j] - (float)hh);
    }
    ((bf16x4*)khi)[i] = h;
    ((bf16x4*)klo)[i] = lo;
}

// ---------------- pre-pass 3: V fp32 [B,S,KVH,D] -> bf16 hi/lo transposed [B,KVH,D,S] ----------------
__global__ __launch_bounds__(512) void transpose_v(const float* __restrict__ V,
                                                   __bf16* __restrict__ vthi,
                                                   __bf16* __restrict__ vtlo) {
    __shared__ float tile[64][65];
    const int bid = blockIdx.x;                 // B*KVH*(S/64)
    const int st  = bid & 31;
    const int kv  = (bid >> 5) % KVH_;
    const int b   = bid / (32 * KVH_);
    const int s0  = st * 64;
    const int tid = threadIdx.x;
    const int c   = tid & 63;
    const int rq  = tid >> 6;                   // 0..7
#pragma unroll
    for (int i = 0; i < 8; i++) {
        const int si = rq + i * 8;
        tile[si][c] = V[(((size_t)b * S_ + s0 + si) * KVH_ + kv) * D_ + c];
    }
    __syncthreads();
#pragma unroll
    for (int i = 0; i < 8; i++) {
        const int di = rq + i * 8;              // d index
        const float x = tile[c][di];            // s index = c
        const __bf16 hh = (__bf16)x;
        const size_t o = (((size_t)b * KVH_ + kv) * D_ + di) * S_ + s0 + c;
        vthi[o] = hh;
        vtlo[o] = (__bf16)(x - (float)hh);
    }
}

// ---------------- main flash-attention kernel (templated on split-K) ----------------
// SPLIT=0: grid NBLK, full key range, writes normalized out.
// SPLIT=1: grid 2*NBLK (bid&1 = key-half), writes raw accumulator A + (m,l) partials.
// Swapped-operand MFMAs; key-permuted K staging keeps P fully in registers (see R8 notes).
// P-hi-only PV: P truncated to bf16; l accumulates the TRUNCATED p so out is a
// self-consistent weighted average (no truncation bias). PV = 2 MFMA/db (vh,vl with ph).
template<int SPLIT>
__global__ __launch_bounds__(256) void attn_main(const unsigned int* __restrict__ bits,
                                                 const float* __restrict__ Q,
                                                 const __bf16* __restrict__ khi,
                                                 const __bf16* __restrict__ klo,
                                                 const __bf16* __restrict__ vthi,
                                                 const __bf16* __restrict__ vtlo,
                                                 float* __restrict__ dst,
                                                 float2* __restrict__ ml) {
    __shared__ __align__(16) __bf16 Kls[2][2][KBLK][64];   // 16 KB
    __shared__ __align__(16) __bf16 Vls[2][2][64][KBLK];   // 16 KB

    const int tid  = threadIdx.x;
    const int wv   = tid >> 6;
    const int lane = tid & 63;
    const int lrow = lane & 15;
    const int lgrp = lane >> 4;

    const int bid = blockIdx.x;
    const int hw  = SPLIT ? (bid & 1) : 0;
    const int blk = SPLIT ? (bid >> 1) : bid;
    const int qt  = blk & 31;
    const int bh  = blk >> 5;
    const int h   = bh % H_;
    const int b   = bh / H_;
    const int kv  = h / G_;
    const int q0  = qt * 64 + wv * 16;
    const int kbase = SPLIT ? hw * (S_ / 2) : 0;
    constexpr int NIT = SPLIT ? (S_ / 2 / KBLK) : (S_ / KBLK);

    // ---- Q fragments (pre-scaled by SCALE) ----
    const float* qp = Q + (((size_t)b * S_ + (q0 + lrow)) * H_ + h) * D_;
    bf16x8 ahi[2], alo[2];
#pragma unroll
    for (int kk = 0; kk < 2; kk++) {
#pragma unroll
        for (int jj = 0; jj < 2; jj++) {
            const float4 v = *(const float4*)(qp + kk * 32 + lgrp * 8 + jj * 4);
            const float xs[4] = {v.x * SCALE, v.y * SCALE, v.z * SCALE, v.w * SCALE};
#pragma unroll
            for (int j = 0; j < 4; j++) {
                const __bf16 hh = (__bf16)xs[j];
                ahi[kk][jj * 4 + j] = hh;
                alo[kk][jj * 4 + j] = (__bf16)(xs[j] - (float)hh);
            }
        }
    }

    f32x4 O[4] = {{0.f,0.f,0.f,0.f},{0.f,0.f,0.f,0.f},{0.f,0.f,0.f,0.f},{0.f,0.f,0.f,0.f}};
    float m = NEG_BIG, l = 0.f;

    const __bf16* khb = khi + (size_t)b * S_ * KVD_ + kv * D_;
    const __bf16* klb = klo + (size_t)b * S_ * KVD_ + kv * D_;
    const __bf16* vhb = vthi + ((size_t)b * KVH_ + kv) * D_ * S_;
    const __bf16* vlb = vtlo + ((size_t)b * KVH_ + kv) * D_ * S_;

    // staging geometry (64 granules of 16B per gload16)
    const int kgi  = wv * 64 + lane;
    const int krho = kgi >> 3;                              // LDS row 0..31
    const int kkey = 8 * ((krho >> 2) & 3) + 4 * (krho >> 4) + (krho & 3);   // permuted key
    const int kcol = (((kgi & 7) ^ (krho & 7)) * 8);        // inverse-swizzled d-offset
    const int vrow = kgi >> 2, vcg = kgi & 3;
    const int vcol = ((vcg ^ ((vrow >> 1) & 3)) * 8);       // inverse-swizzled key-offset

    const __bf16* khsrc = khb + (size_t)(kbase + kkey) * KVD_ + kcol;
    const __bf16* klsrc = klb + (size_t)(kbase + kkey) * KVD_ + kcol;
    const __bf16* vhsrc = vhb + (size_t)vrow * S_ + kbase + vcol;
    const __bf16* vlsrc = vlb + (size_t)vrow * S_ + kbase + vcol;
    const unsigned int* bptr = bits + ((size_t)b * S_ + q0 + lrow) * SW_ + (SPLIT ? hw * NIT : 0);

    gload16(khsrc, &Kls[0][0][wv * 8][0]);
    gload16(klsrc, &Kls[0][1][wv * 8][0]);
    gload16(vhsrc, &Vls[0][0][wv * 16][0]);
    gload16(vlsrc, &Vls[0][1][wv * 16][0]);
    khsrc += (size_t)KBLK * KVD_;
    klsrc += (size_t)KBLK * KVD_;
    vhsrc += KBLK;
    vlsrc += KBLK;
    __syncthreads();

    for (int kt = 0; kt < NIT; kt++) {
        const int cur = kt & 1;
        const unsigned w = *bptr++;

        if (kt + 1 < NIT) {
            gload16(khsrc, &Kls[cur ^ 1][0][wv * 8][0]);
            gload16(klsrc, &Kls[cur ^ 1][1][wv * 8][0]);
            gload16(vhsrc, &Vls[cur ^ 1][0][wv * 16][0]);
            gload16(vlsrc, &Vls[cur ^ 1][1][wv * 16][0]);
            khsrc += (size_t)KBLK * KVD_;
            klsrc += (size_t)KBLK * KVD_;
            vhsrc += KBLK;
            vlsrc += KBLK;
        }

        // ---- QK^T (swapped): s[t][r] = S[key=8*lgrp+4t+r][q=lrow] ----
        f32x4 s[2];
#pragma unroll
        for (int t = 0; t < 2; t++) {
            const int row = t * 16 + lrow;
            const int sw  = row & 7;
            const bf16x8 bh0 = *(const bf16x8*)&Kls[cur][0][row][(lgrp ^ sw) * 8];
            const bf16x8 bh1 = *(const bf16x8*)&Kls[cur][0][row][((4 + lgrp) ^ sw) * 8];
            const bf16x8 bl0 = *(const bf16x8*)&Kls[cur][1][row][(lgrp ^ sw) * 8];
            const bf16x8 bl1 = *(const bf16x8*)&Kls[cur][1][row][((4 + lgrp) ^ sw) * 8];
            f32x4 acc = {0.f, 0.f, 0.f, 0.f};
            acc = MFMA(bh0, ahi[0], acc);
            acc = MFMA(bh0, alo[0], acc);
            acc = MFMA(bl0, ahi[0], acc);
            acc = MFMA(bh1, ahi[1], acc);
            acc = MFMA(bh1, alo[1], acc);
            acc = MFMA(bl1, ahi[1], acc);
            s[t] = acc;
        }

        // ---- mask + in-register row-max ----
        float pmax = NEG_BIG;
#pragma unroll
        for (int t = 0; t < 2; t++) {
#pragma unroll
            for (int r = 0; r < 4; r++) {
                const int bit = 8 * lgrp + 4 * t + r;
                const float sv = ((w >> bit) & 1u) ? s[t][r] : NEG_BIG;
                s[t][r] = sv;
                pmax = fmaxf(pmax, sv);
            }
        }
        pmax = fmaxf(pmax, __shfl_xor(pmax, 16));
        pmax = fmaxf(pmax, __shfl_xor(pmax, 32));

        // ---- defer-max rescale ----
        if (!__all(pmax <= m + DEFER_THR)) {
            const float mn = fmaxf(m, pmax);
            const float f  = __expf(m - mn);
            m = mn;
            l *= f;
#pragma unroll
            for (int db = 0; db < 4; db++) {
                f32x4 o = O[db];
                o[0] *= f; o[1] *= f; o[2] *= f; o[3] *= f;
                O[db] = o;
            }
        }

        // ---- exp + truncate-pack (P-hi only; l accumulates TRUNCATED p) ----
        unsigned hwd[4];
#pragma unroll
        for (int t = 0; t < 2; t++) {
#pragma unroll
            for (int pr = 0; pr < 2; pr++) {
                const float e0 = __expf(s[t][2 * pr]     - m);
                const float e1 = __expf(s[t][2 * pr + 1] - m);
                const unsigned u0 = __builtin_bit_cast(unsigned, e0) & 0xFFFF0000u;
                const unsigned u1 = __builtin_bit_cast(unsigned, e1) & 0xFFFF0000u;
                l += __builtin_bit_cast(float, u0) + __builtin_bit_cast(float, u1);
                hwd[2 * t + pr] = pack_hi16(u0, u1);
            }
        }
        i32x4 wh;
#pragma unroll
        for (int i = 0; i < 4; i++) wh[i] = (int)hwd[i];
        const bf16x8 ph = __builtin_bit_cast(bf16x8, wh);

        // ---- PV (swapped): O^T[d][q] = MFMA(V, P) ----
#pragma unroll
        for (int db = 0; db < 4; db++) {
            const int row = db * 16 + lrow;
            const int sw  = (row >> 1) & 3;
            const bf16x8 vh = *(const bf16x8*)&Vls[cur][0][row][(lgrp ^ sw) * 8];
            const bf16x8 vl = *(const bf16x8*)&Vls[cur][1][row][(lgrp ^ sw) * 8];
            O[db] = MFMA(vh, ph, O[db]);
            O[db] = MFMA(vl, ph, O[db]);
        }

        __syncthreads();
    }

    // ---- epilogue ----
    float lv = l;
    lv += __shfl_xor(lv, 16);
    lv += __shfl_xor(lv, 32);

    if constexpr (SPLIT) {
        // raw partials: A[(hw*NBLK+blk)][q 0..63][d 0..63], ml[(hw*NBLK+blk)][q]
        const size_t prow = ((size_t)(hw * NBLK + blk) * 64 + wv * 16 + lrow) * 64;
#pragma unroll
        for (int db = 0; db < 4; db++)
            *(f32x4*)&dst[prow + db * 16 + lgrp * 4] = O[db];
        if (lgrp == 0)
            ml[(size_t)(hw * NBLK + blk) * 64 + wv * 16 + lrow] = make_float2(m, lv);
    } else {
        const float inv = 1.0f / lv;
        float* op = dst + ((size_t)b * S_ + q0 + lrow) * HD_ + h * D_ + lgrp * 4;
#pragma unroll
        for (int db = 0; db < 4; db++) {
            f32x4 o = O[db];
            o[0] *= inv; o[1] *= inv; o[2] *= inv; o[3] *= inv;
            *(f32x4*)(op + db * 16) = o;
        }
    }
}

// ---------------- split-K combine: out = (A0 f0 + A1 f1) / (l0 f0 + l1 f1) ----------------
__global__ __launch_bounds__(256) void combine(const float* __restrict__ A,
                                               const float2* __restrict__ ml,
                                               float* __restrict__ out) {
    const int tid = threadIdx.x;
    const int row = blockIdx.x * 4 + (tid >> 6);           // over B*H*S
    const int d   = tid & 63;
    const int b   = row / (H_ * S_);
    const int rem = row - b * (H_ * S_);
    const int h   = rem >> 11;                             // /S_
    const int q   = rem & (S_ - 1);
    const int blkid = (b * H_ + h) * 32 + (q >> 6);
    const int qi  = q & 63;
    const float2 ml0 = ml[(size_t)blkid * 64 + qi];
    const float2 ml1 = ml[(size_t)(NBLK + blkid) * 64 + qi];
    const float M  = fmaxf(ml0.x, ml1.x);
    const float f0 = __expf(ml0.x - M);
    const float f1 = __expf(ml1.x - M);
    const float inv = 1.0f / (ml0.y * f0 + ml1.y * f1);
    const float a0 = A[((size_t)blkid * 64 + qi) * 64 + d];
    const float a1 = A[((size_t)(NBLK + blkid) * 64 + qi) * 64 + d];
    out[((size_t)b * S_ + q) * HD_ + h * D_ + d] = (a0 * f0 + a1 * f1) * inv;
}

extern "C" void kernel_launch(void* const* d_in, const int* in_sizes, int n_in,
                              void* d_out, int out_size, void* d_ws, size_t ws_size,
                              hipStream_t stream) {
    const int*   mask = (const int*)d_in[0];
    const float* Q    = (const float*)d_in[1];
    const float* K    = (const float*)d_in[2];
    const float* V    = (const float*)d_in[3];
    float*       out  = (float*)d_out;

    char* ws = (char*)d_ws;
    unsigned int* bits = (unsigned int*)ws;
    const size_t KV_BYTES = (size_t)B_ * S_ * KVH_ * D_ * sizeof(__bf16);   // 2,621,440
    __bf16* khi  = (__bf16*)(ws + (1 << 20));
    __bf16* klo  = (__bf16*)(ws + (1 << 20) + KV_BYTES);
    __bf16* vthi = (__bf16*)(ws + (1 << 20) + 2 * KV_BYTES);
    __bf16* vtlo = (__bf16*)(ws + (1 << 20) + 3 * KV_BYTES);

    // split-K partials (beyond the 11,534,336 B above)
    const size_t PART_OFF = (size_t)(1 << 20) + 4 * KV_BYTES;                // 11,534,336
    const size_t A_BYTES  = (size_t)2 * NBLK * 64 * 64 * sizeof(float);     // 31,457,280
    const size_t ML_BYTES = (size_t)2 * NBLK * 64 * sizeof(float2);         //    983,040
    const size_t REQ      = PART_OFF + A_BYTES + ML_BYTES;                  // ~44 MB
    float*  Apart = (float*)(ws + PART_OFF);
    float2* mlp   = (float2*)(ws + PART_OFF + A_BYTES);

    bitpack<<<2048, 256, 0, stream>>>(mask, bits);
    conv_k<<<(B_ * S_ * KVH_ * D_) / (256 * 4), 256, 0, stream>>>(K, khi, klo);
    transpose_v<<<B_ * KVH_ * (S_ / 64), 512, 0, stream>>>(V, vthi, vtlo);

    if (ws_size >= REQ) {
        attn_main<1><<<2 * NBLK, 256, 0, stream>>>(bits, Q, khi, klo, vthi, vtlo, Apart, mlp);
        combine<<<(B_ * H_ * S_) / 4, 256, 0, stream>>>(Apart, mlp, out);
    } else {
        attn_main<0><<<NBLK, 256, 0, stream>>>(bits, Q, khi, klo, vthi, vtlo, out, nullptr);
    }
}

// Round 14
// 224.354 us; speedup vs baseline: 1.0473x; 1.0473x over previous
//
#include <hip/hip_runtime.h>
#include <hip/hip_bf16.h>

#define B_    2
#define S_    2048
#define H_    15
#define KVH_  5
#define G_    3
#define D_    64
#define KVD_  (KVH_ * D_)      // 320
#define HD_   (H_ * D_)        // 960
#define SW_   (S_ / 32)        // 64 mask words per row
#define KBLK  32
#define ITER  (S_ / KBLK)      // 64
#define NBLK  960              // B*H*(S/64)

// SCALE * log2(e): softmax entirely in exp2 domain (v_exp_f32 computes 2^x natively)
constexpr float SCALE2  = 0.125f * 1.44269504088896340736f;
constexpr float NEG_BIG = -3.0e38f;
constexpr float DEFER_THR = 11.0f;     // defer-max threshold in log2 units (~8 nats)

typedef __bf16  bf16x8 __attribute__((ext_vector_type(8)));
typedef __bf16  bf16x4 __attribute__((ext_vector_type(4)));
typedef float   f32x4  __attribute__((ext_vector_type(4)));
typedef int     i32x4  __attribute__((ext_vector_type(4)));

#define MFMA(a, b, c) __builtin_amdgcn_mfma_f32_16x16x32_bf16((a), (b), (c), 0, 0, 0)

// async global->LDS, 16B per lane; LDS dest is wave-uniform base, lane i lands at base+i*16
__device__ __forceinline__ void gload16(const void* g, void* l) {
    __builtin_amdgcn_global_load_lds(
        (const __attribute__((address_space(1))) unsigned int*)g,
        (__attribute__((address_space(3))) unsigned int*)l, 16, 0, 0);
}

// pack top-16-bits of two f32 into one bf16x2 word: low16 = trunc-bf16(even), high16 = trunc-bf16(odd)
__device__ __forceinline__ unsigned pack_hi16(unsigned even_elem, unsigned odd_elem) {
    return __builtin_amdgcn_perm(odd_elem, even_elem, 0x07060302u);
}

// ---------------- fused pre-pass: one kernel, block-range partitioned ----------------
// blocks [0,320):    V fp32 [B,S,KVH,D] -> bf16 hi/lo transposed [B,KVH,D,S]
// blocks [320,960):  K fp32 -> bf16 hi/lo (640 blocks x 512 thr x 1 float4 = exact)
// blocks [960,1984): mask int32 -> bitmask (grid-stride, 16 iters)
__global__ __launch_bounds__(512) void fused_pre(const int* __restrict__ mask,
                                                 const float* __restrict__ K,
                                                 const float* __restrict__ V,
                                                 unsigned int* __restrict__ bits,
                                                 __bf16* __restrict__ khi,
                                                 __bf16* __restrict__ klo,
                                                 __bf16* __restrict__ vthi,
                                                 __bf16* __restrict__ vtlo) {
    __shared__ float tile[64][65];
    const int blk = blockIdx.x;
    const int tid = threadIdx.x;

    if (blk < 320) {
        // ---- transpose V ----
        const int st  = blk & 31;
        const int kv  = (blk >> 5) % KVH_;
        const int b   = blk / (32 * KVH_);
        const int s0  = st * 64;
        const int c   = tid & 63;
        const int rq  = tid >> 6;               // 0..7
#pragma unroll
        for (int i = 0; i < 8; i++) {
            const int si = rq + i * 8;
            tile[si][c] = V[(((size_t)b * S_ + s0 + si) * KVH_ + kv) * D_ + c];
        }
        __syncthreads();
#pragma unroll
        for (int i = 0; i < 8; i++) {
            const int di = rq + i * 8;          // d index
            const float x = tile[c][di];        // s index = c
            const __bf16 hh = (__bf16)x;
            const size_t o = (((size_t)b * KVH_ + kv) * D_ + di) * S_ + s0 + c;
            vthi[o] = hh;
            vtlo[o] = (__bf16)(x - (float)hh);
        }
    } else if (blk < 960) {
        // ---- convert K ----
        const int i = (blk - 320) * 512 + tid;  // over (B*S*KVH*D)/4 = 327680
        const float4 v = ((const float4*)K)[i];
        const float xs[4] = {v.x, v.y, v.z, v.w};
        bf16x4 h, lo;
#pragma unroll
        for (int j = 0; j < 4; j++) {
            __bf16 hh = (__bf16)xs[j];
            h[j]  = hh;
            lo[j] = (__bf16)(xs[j] - (float)hh);
        }
        ((bf16x4*)khi)[i] = h;
        ((bf16x4*)klo)[i] = lo;
    } else {
        // ---- bitpack mask ----
        const int lane = tid & 63;
        const int stride = 1024 * 512;
        for (int i = (blk - 960) * 512 + tid; i < B_ * S_ * S_; i += stride) {
            unsigned long long bal = __ballot(mask[i] != 0);
            if (lane == 0)       bits[i >> 5] = (unsigned int)bal;
            else if (lane == 32) bits[i >> 5] = (unsigned int)(bal >> 32);
        }
    }
}

// ---------------- main flash-attention kernel ----------------
// grid NBLK blocks of 256 (4 waves); wave w handles 16 q rows, KBLK=32 keys/iter.
// Swapped-operand MFMAs; key-permuted K staging keeps P in registers (R8 notes).
// P-hi-only PV (truncated P; l accumulates the SAME truncated P -> self-consistent).
// l computed by MFMA with an all-ones A operand: accL = MFMA(ones, ph, accL) sums
// all 32 keys of the tile AND cross-lane-reduces -- no VALU adds, no epilogue shfl.
// Softmax in exp2 domain (log2e folded into Q scale): exp2f = bare v_exp_f32.
__global__ __launch_bounds__(256) void attn_main(const unsigned int* __restrict__ bits,
                                                 const float* __restrict__ Q,
                                                 const __bf16* __restrict__ khi,
                                                 const __bf16* __restrict__ klo,
                                                 const __bf16* __restrict__ vthi,
                                                 const __bf16* __restrict__ vtlo,
                                                 float* __restrict__ out) {
    __shared__ __align__(16) __bf16 Kls[2][2][KBLK][64];   // 16 KB
    __shared__ __align__(16) __bf16 Vls[2][2][64][KBLK];   // 16 KB

    const int tid  = threadIdx.x;
    const int wv   = tid >> 6;
    const int lane = tid & 63;
    const int lrow = lane & 15;
    const int lgrp = lane >> 4;

    const int bid = blockIdx.x;
    const int qt  = bid & 31;
    const int bh  = bid >> 5;
    const int h   = bh % H_;
    const int b   = bh / H_;
    const int kv  = h / G_;
    const int q0  = qt * 64 + wv * 16;

    // ---- Q fragments (pre-scaled by SCALE2 = scale * log2e) ----
    const float* qp = Q + (((size_t)b * S_ + (q0 + lrow)) * H_ + h) * D_;
    bf16x8 ahi[2], alo[2];
#pragma unroll
    for (int kk = 0; kk < 2; kk++) {
#pragma unroll
        for (int jj = 0; jj < 2; jj++) {
            const float4 v = *(const float4*)(qp + kk * 32 + lgrp * 8 + jj * 4);
            const float xs[4] = {v.x * SCALE2, v.y * SCALE2, v.z * SCALE2, v.w * SCALE2};
#pragma unroll
            for (int j = 0; j < 4; j++) {
                const __bf16 hh = (__bf16)xs[j];
                ahi[kk][jj * 4 + j] = hh;
                alo[kk][jj * 4 + j] = (__bf16)(xs[j] - (float)hh);
            }
        }
    }

    const i32x4 onesw = {0x3F803F80, 0x3F803F80, 0x3F803F80, 0x3F803F80};
    const bf16x8 ones = __builtin_bit_cast(bf16x8, onesw);   // 8x bf16 1.0

    f32x4 O[4] = {{0.f,0.f,0.f,0.f},{0.f,0.f,0.f,0.f},{0.f,0.f,0.f,0.f},{0.f,0.f,0.f,0.f}};
    f32x4 accL = {0.f, 0.f, 0.f, 0.f};
    float m = NEG_BIG;

    const __bf16* khb = khi + (size_t)b * S_ * KVD_ + kv * D_;
    const __bf16* klb = klo + (size_t)b * S_ * KVD_ + kv * D_;
    const __bf16* vhb = vthi + ((size_t)b * KVH_ + kv) * D_ * S_;
    const __bf16* vlb = vtlo + ((size_t)b * KVH_ + kv) * D_ * S_;

    // staging geometry (64 granules of 16B per gload16)
    const int kgi  = wv * 64 + lane;
    const int krho = kgi >> 3;                              // LDS row 0..31
    const int kkey = 8 * ((krho >> 2) & 3) + 4 * (krho >> 4) + (krho & 3);   // permuted key
    const int kcol = (((kgi & 7) ^ (krho & 7)) * 8);        // inverse-swizzled d-offset
    const int vrow = kgi >> 2, vcg = kgi & 3;
    const int vcol = ((vcg ^ ((vrow >> 1) & 3)) * 8);       // inverse-swizzled key-offset

    const __bf16* khsrc = khb + (size_t)kkey * KVD_ + kcol;
    const __bf16* klsrc = klb + (size_t)kkey * KVD_ + kcol;
    const __bf16* vhsrc = vhb + (size_t)vrow * S_ + vcol;
    const __bf16* vlsrc = vlb + (size_t)vrow * S_ + vcol;
    const unsigned int* bptr = bits + ((size_t)b * S_ + q0 + lrow) * SW_;

    gload16(khsrc, &Kls[0][0][wv * 8][0]);
    gload16(klsrc, &Kls[0][1][wv * 8][0]);
    gload16(vhsrc, &Vls[0][0][wv * 16][0]);
    gload16(vlsrc, &Vls[0][1][wv * 16][0]);
    khsrc += (size_t)KBLK * KVD_;
    klsrc += (size_t)KBLK * KVD_;
    vhsrc += KBLK;
    vlsrc += KBLK;
    __syncthreads();

    for (int kt = 0; kt < ITER; kt++) {
        const int cur = kt & 1;
        const unsigned w = *bptr++;

        if (kt + 1 < ITER) {
            gload16(khsrc, &Kls[cur ^ 1][0][wv * 8][0]);
            gload16(klsrc, &Kls[cur ^ 1][1][wv * 8][0]);
            gload16(vhsrc, &Vls[cur ^ 1][0][wv * 16][0]);
            gload16(vlsrc, &Vls[cur ^ 1][1][wv * 16][0]);
            khsrc += (size_t)KBLK * KVD_;
            klsrc += (size_t)KBLK * KVD_;
            vhsrc += KBLK;
            vlsrc += KBLK;
        }

        // ---- QK^T (swapped): s[t][r] = S[key=8*lgrp+4t+r][q=lrow], log2 domain ----
        f32x4 s[2];
#pragma unroll
        for (int t = 0; t < 2; t++) {
            const int row = t * 16 + lrow;
            const int sw  = row & 7;
            const bf16x8 bh0 = *(const bf16x8*)&Kls[cur][0][row][(lgrp ^ sw) * 8];
            const bf16x8 bh1 = *(const bf16x8*)&Kls[cur][0][row][((4 + lgrp) ^ sw) * 8];
            const bf16x8 bl0 = *(const bf16x8*)&Kls[cur][1][row][(lgrp ^ sw) * 8];
            const bf16x8 bl1 = *(const bf16x8*)&Kls[cur][1][row][((4 + lgrp) ^ sw) * 8];
            f32x4 acc = {0.f, 0.f, 0.f, 0.f};
            acc = MFMA(bh0, ahi[0], acc);
            acc = MFMA(bh0, alo[0], acc);
            acc = MFMA(bl0, ahi[0], acc);
            acc = MFMA(bh1, ahi[1], acc);
            acc = MFMA(bh1, alo[1], acc);
            acc = MFMA(bl1, ahi[1], acc);
            s[t] = acc;
        }

        // ---- mask + in-register row-max ----
        float pmax = NEG_BIG;
#pragma unroll
        for (int t = 0; t < 2; t++) {
#pragma unroll
            for (int r = 0; r < 4; r++) {
                const int bit = 8 * lgrp + 4 * t + r;
                const float sv = ((w >> bit) & 1u) ? s[t][r] : NEG_BIG;
                s[t][r] = sv;
                pmax = fmaxf(pmax, sv);
            }
        }
        pmax = fmaxf(pmax, __shfl_xor(pmax, 16));
        pmax = fmaxf(pmax, __shfl_xor(pmax, 32));

        // ---- defer-max rescale (log2 domain) ----
        if (!__all(pmax <= m + DEFER_THR)) {
            const float mn = fmaxf(m, pmax);
            const float f  = exp2f(m - mn);
            m = mn;
            accL[0] *= f; accL[1] *= f; accL[2] *= f; accL[3] *= f;
#pragma unroll
            for (int db = 0; db < 4; db++) {
                f32x4 o = O[db];
                o[0] *= f; o[1] *= f; o[2] *= f; o[3] *= f;
                O[db] = o;
            }
        }

        // ---- exp2 + truncate-pack (P-hi only) ----
        unsigned hwd[4];
#pragma unroll
        for (int t = 0; t < 2; t++) {
#pragma unroll
            for (int pr = 0; pr < 2; pr++) {
                const float e0 = exp2f(s[t][2 * pr]     - m);
                const float e1 = exp2f(s[t][2 * pr + 1] - m);
                hwd[2 * t + pr] = pack_hi16(__builtin_bit_cast(unsigned, e0),
                                            __builtin_bit_cast(unsigned, e1));
            }
        }
        i32x4 wh;
#pragma unroll
        for (int i = 0; i < 4; i++) wh[i] = (int)hwd[i];
        const bf16x8 ph = __builtin_bit_cast(bf16x8, wh);

        // ---- l via MFMA: accL[r] = sum_k P~[k][q]  (all rows identical) ----
        accL = MFMA(ones, ph, accL);

        // ---- PV (swapped): O^T[d][q] = MFMA(V, P) ----
#pragma unroll
        for (int db = 0; db < 4; db++) {
            const int row = db * 16 + lrow;
            const int sw  = (row >> 1) & 3;
            const bf16x8 vh = *(const bf16x8*)&Vls[cur][0][row][(lgrp ^ sw) * 8];
            const bf16x8 vl = *(const bf16x8*)&Vls[cur][1][row][(lgrp ^ sw) * 8];
            O[db] = MFMA(vh, ph, O[db]);
            O[db] = MFMA(vl, ph, O[db]);
        }

        __syncthreads();
    }

    // ---- epilogue: l already complete per-lane (MFMA cross-lane reduced) ----
    const float inv = 1.0f / accL[0];
    float* op = out + ((size_t)b * S_ + q0 + lrow) * HD_ + h * D_ + lgrp * 4;
#pragma unroll
    for (int db = 0; db < 4; db++) {
        f32x4 o = O[db];
        o[0] *= inv; o[1] *= inv; o[2] *= inv; o[3] *= inv;
        *(f32x4*)(op + db * 16) = o;
    }
}

extern "C" void kernel_launch(void* const* d_in, const int* in_sizes, int n_in,
                              void* d_out, int out_size, void* d_ws, size_t ws_size,
                              hipStream_t stream) {
    const int*   mask = (const int*)d_in[0];
    const float* Q    = (const float*)d_in[1];
    const float* K    = (const float*)d_in[2];
    const float* V    = (const float*)d_in[3];
    float*       out  = (float*)d_out;

    char* ws = (char*)d_ws;
    unsigned int* bits = (unsigned int*)ws;
    const size_t KV_BYTES = (size_t)B_ * S_ * KVH_ * D_ * sizeof(__bf16);   // 2,621,440
    __bf16* khi  = (__bf16*)(ws + (1 << 20));
    __bf16* klo  = (__bf16*)(ws + (1 << 20) + KV_BYTES);
    __bf16* vthi = (__bf16*)(ws + (1 << 20) + 2 * KV_BYTES);
    __bf16* vtlo = (__bf16*)(ws + (1 << 20) + 3 * KV_BYTES);

    fused_pre<<<1984, 512, 0, stream>>>(mask, K, V, bits, khi, klo, vthi, vtlo);
    attn_main<<<NBLK, 256, 0, stream>>>(bits, Q, khi, klo, vthi, vtlo, out);
}